// Round 7
// baseline (292.047 us; speedup 1.0000x reference)
//
#include <hip/hip_runtime.h>

#define GRID3 32768  // 32^3
#define FDIM 64
#define CHUNK 512    // counts per scan chunk
#define GBLOCKS 2048 // persistent gather blocks (8192 waves)

// Order-preserving float<->uint encoding (monotonic: enc(a)<enc(b) iff a<b)
__device__ __forceinline__ unsigned int enc_f32(float f) {
    unsigned int u = __float_as_uint(f);
    return (u & 0x80000000u) ? ~u : (u | 0x80000000u);
}
__device__ __forceinline__ float dec_f32(unsigned int u) {
    u = (u & 0x80000000u) ? (u ^ 0x80000000u) : ~u;
    return __uint_as_float(u);
}

__device__ __forceinline__ int bin_of(float x, float y, float z,
                                      float pmin, float denom) {
    // Reference op order exactly: ((v - pmin) / denom) * 32, floor.
    // Values >= 0, so int-trunc == floor.
    int vx = (int)(((x - pmin) / denom) * 32.0f);
    int vy = (int)(((y - pmin) / denom) * 32.0f);
    int vz = (int)(((z - pmin) / denom) * 32.0f);
    vx = min(max(vx, 0), 31);
    vy = min(max(vy, 0), 31);
    vz = min(max(vz, 0), 31);
    return (vx << 10) + (vy << 5) + vz;
}

__global__ void init_ws_kernel(unsigned int* ws) {
    ws[0] = 0xFFFFFFFFu;  // encoded min
    ws[1] = 0u;           // encoded max
    ws[2] = 0u;           // occupied-bin counter
}

__global__ void minmax_kernel(const float* __restrict__ pts, int n,
                              unsigned int* __restrict__ ws) {
    float lmin = INFINITY, lmax = -INFINITY;
    const float4* p4 = reinterpret_cast<const float4*>(pts);
    const int n4 = n >> 2;
    for (int i = blockIdx.x * blockDim.x + threadIdx.x; i < n4;
         i += gridDim.x * blockDim.x) {
        float4 v = p4[i];
        lmin = fminf(lmin, fminf(fminf(v.x, v.y), fminf(v.z, v.w)));
        lmax = fmaxf(lmax, fmaxf(fmaxf(v.x, v.y), fmaxf(v.z, v.w)));
    }
    for (int i = (n4 << 2) + blockIdx.x * blockDim.x + threadIdx.x; i < n;
         i += gridDim.x * blockDim.x) {
        float v = pts[i];
        lmin = fminf(lmin, v);
        lmax = fmaxf(lmax, v);
    }
    __shared__ float smin[256], smax[256];
    smin[threadIdx.x] = lmin;
    smax[threadIdx.x] = lmax;
    __syncthreads();
    for (int s = 128; s > 0; s >>= 1) {
        if (threadIdx.x < (unsigned)s) {
            smin[threadIdx.x] = fminf(smin[threadIdx.x], smin[threadIdx.x + s]);
            smax[threadIdx.x] = fmaxf(smax[threadIdx.x], smax[threadIdx.x + s]);
        }
        __syncthreads();
    }
    if (threadIdx.x == 0) {
        atomicMin(&ws[0], enc_f32(smin[0]));
        atomicMax(&ws[1], enc_f32(smax[0]));
    }
}

// Per-point histogram: 400k scattered 4B atomics over a 512KB L2-resident array.
__global__ void count_kernel(const float* __restrict__ pts,
                             const unsigned int* __restrict__ ws,
                             unsigned int* __restrict__ cnt,
                             int ntot, int N) {
    int i = blockIdx.x * blockDim.x + threadIdx.x;
    if (i >= ntot) return;
    float pmin = dec_f32(ws[0]);
    float denom = dec_f32(ws[1]) - pmin + 1e-6f;
    int bin = (i / N) * GRID3 +
              bin_of(pts[i * 3], pts[i * 3 + 1], pts[i * 3 + 2], pmin, denom);
    atomicAdd(&cnt[bin], 1u);
}

// Compact: append every occupied bin id to occ[] (order irrelevant).
// Runs on RAW counts, before the in-place scan overwrites them.
__global__ void compact_kernel(const unsigned int* __restrict__ cnt,
                               unsigned int* __restrict__ occ,
                               unsigned int* __restrict__ noccp, int nbins) {
    int i = blockIdx.x * blockDim.x + threadIdx.x;
    if (i >= nbins) return;
    if (cnt[i] != 0u) {
        unsigned int pos = atomicAdd(noccp, 1u);
        occ[pos] = (unsigned int)i;
    }
}

// Scan pass A: per-chunk sums.
__global__ __launch_bounds__(256)
void scanA_kernel(const unsigned int* __restrict__ cnt,
                  unsigned int* __restrict__ bsum, int nbins) {
    __shared__ unsigned int s[256];
    int base = blockIdx.x * CHUNK;
    int t = threadIdx.x;
    unsigned int a = (base + t < nbins) ? cnt[base + t] : 0u;
    unsigned int b = (base + t + 256 < nbins) ? cnt[base + t + 256] : 0u;
    s[t] = a + b;
    __syncthreads();
    for (int st = 128; st > 0; st >>= 1) {
        if (t < st) s[t] += s[t + st];
        __syncthreads();
    }
    if (t == 0) bsum[blockIdx.x] = s[0];
}

// Scan pass B: exclusive scan of chunk sums (single block, <=1024 chunks).
__global__ __launch_bounds__(1024)
void scanB_kernel(unsigned int* __restrict__ bsum, int nchunks) {
    __shared__ unsigned int s[1024];
    int t = threadIdx.x;
    unsigned int own = (t < nchunks) ? bsum[t] : 0u;
    s[t] = own;
    __syncthreads();
    for (int off = 1; off < 1024; off <<= 1) {
        unsigned int v = (t >= off) ? s[t - off] : 0u;
        __syncthreads();
        s[t] += v;
        __syncthreads();
    }
    if (t < nchunks) bsum[t] = s[t] - own;  // exclusive
}

// Scan pass C: within-chunk exclusive scan + chunk offset, in place.
__global__ __launch_bounds__(256)
void scanC_kernel(unsigned int* __restrict__ cnt,
                  const unsigned int* __restrict__ bsum, int nbins) {
    __shared__ unsigned int s[256];
    int t = threadIdx.x;
    int base = blockIdx.x * CHUNK;
    int i0 = base + 2 * t;
    unsigned int a = (i0 < nbins) ? cnt[i0] : 0u;
    unsigned int b = (i0 + 1 < nbins) ? cnt[i0 + 1] : 0u;
    unsigned int p = a + b;
    s[t] = p;
    __syncthreads();
    for (int off = 1; off < 256; off <<= 1) {
        unsigned int v = (t >= off) ? s[t - off] : 0u;
        __syncthreads();
        s[t] += v;
        __syncthreads();
    }
    unsigned int excl = s[t] - p + bsum[blockIdx.x];
    if (i0 < nbins) cnt[i0] = excl;
    if (i0 + 1 < nbins) cnt[i0 + 1] = excl + a;
}

// Fill: pos = cursor[bin]++ ; idx[pos] = point. After this pass,
// cursor[bin] == end offset of bin (== start offset of bin+1).
__global__ void fill_kernel(const float* __restrict__ pts,
                            const unsigned int* __restrict__ ws,
                            unsigned int* __restrict__ cursor,
                            unsigned int* __restrict__ idx,
                            int ntot, int N) {
    int i = blockIdx.x * blockDim.x + threadIdx.x;
    if (i >= ntot) return;
    float pmin = dec_f32(ws[0]);
    float denom = dec_f32(ws[1]) - pmin + 1e-6f;
    int bin = (i / N) * GRID3 +
              bin_of(pts[i * 3], pts[i * 3 + 1], pts[i * 3 + 2], pmin, denom);
    unsigned int pos = atomicAdd(&cursor[bin], 1u);
    idx[pos] = (unsigned int)i;
}

// Persistent gather over OCCUPIED bins only (grid-stride). 8192 waves, each
// handling ~nocc/8192 bins with the proven unroll-16 body. Empty bins are
// never visited (output memset provides the zero background).
__global__ __launch_bounds__(256)
void gatherocc_kernel(const float* __restrict__ feat,
                      const unsigned int* __restrict__ cursor,
                      const unsigned int* __restrict__ idx,
                      const unsigned int* __restrict__ occ,
                      const unsigned int* __restrict__ noccp,
                      float* __restrict__ out) {
    int wid = blockIdx.x * 4 + (threadIdx.x >> 6);
    int lane = threadIdx.x & 63;
    int nocc = (int)*noccp;                  // uniform broadcast load
    const int nwaves = GBLOCKS * 4;
    const float* fl = feat + lane;

    for (int w = wid; w < nocc; w += nwaves) {
        int bin = (int)occ[w];
        unsigned int s = bin ? cursor[bin - 1] : 0u;
        unsigned int e = cursor[bin];
        float acc = 0.0f;  // zeros-init grid == implicit max with 0 (reference)
        unsigned int k = s;
        for (; k + 16 <= e; k += 16) {
            unsigned int p[16];
#pragma unroll
            for (int j = 0; j < 16; ++j) p[j] = idx[k + j];
            float f[16];
#pragma unroll
            for (int j = 0; j < 16; ++j) f[j] = fl[(size_t)p[j] * FDIM];
            float m = f[0];
#pragma unroll
            for (int j = 1; j < 16; ++j) m = fmaxf(m, f[j]);
            acc = fmaxf(acc, m);
        }
        for (; k < e; ++k)
            acc = fmaxf(acc, fl[(size_t)idx[k] * FDIM]);
        out[(size_t)bin * FDIM + lane] = acc;
    }
}

// ---- Fallback: R4 bin-centric gather over ALL bins (proven) ----
__global__ __launch_bounds__(256)
void gather_kernel(const float* __restrict__ feat,
                   const unsigned int* __restrict__ cursor,
                   const unsigned int* __restrict__ idx,
                   float* __restrict__ out, int nbins) {
    int bin = blockIdx.x * 4 + (threadIdx.x >> 6);
    int lane = threadIdx.x & 63;
    if (bin >= nbins) return;
    unsigned int s = bin ? cursor[bin - 1] : 0u;
    unsigned int e = cursor[bin];
    const float* fl = feat + lane;
    float acc = 0.0f;
    unsigned int k = s;
    for (; k + 16 <= e; k += 16) {
        unsigned int p[16];
#pragma unroll
        for (int j = 0; j < 16; ++j) p[j] = idx[k + j];
        float f[16];
#pragma unroll
        for (int j = 0; j < 16; ++j) f[j] = fl[(size_t)p[j] * FDIM];
        float m = f[0];
#pragma unroll
        for (int j = 1; j < 16; ++j) m = fmaxf(m, f[j]);
        acc = fmaxf(acc, m);
    }
    for (; k < e; ++k)
        acc = fmaxf(acc, fl[(size_t)idx[k] * FDIM]);
    out[(size_t)bin * FDIM + lane] = acc;
}

// ---- Fallback: round-0 atomic scatter ----
__global__ void scatter_kernel(const float* __restrict__ pts,
                               const float* __restrict__ feat,
                               const unsigned int* __restrict__ ws,
                               unsigned int* __restrict__ out,
                               int ntot, int N) {
    int lane = threadIdx.x & 63;
    int p = blockIdx.x * 4 + (threadIdx.x >> 6);
    if (p >= ntot) return;
    float pmin = dec_f32(ws[0]);
    float denom = dec_f32(ws[1]) - pmin + 1e-6f;
    int gidx = bin_of(pts[p * 3], pts[p * 3 + 1], pts[p * 3 + 2], pmin, denom);
    int b = p / N;
    float f = feat[(size_t)p * FDIM + lane];
    if (f > 0.0f) {
        unsigned int* addr = out + ((size_t)b * GRID3 + gidx) * FDIM + lane;
        atomicMax(addr, __float_as_uint(f));
    }
}

extern "C" void kernel_launch(void* const* d_in, const int* in_sizes, int n_in,
                              void* d_out, int out_size, void* d_ws, size_t ws_size,
                              hipStream_t stream) {
    const float* pts = (const float*)d_in[0];
    const float* feat = (const float*)d_in[1];
    unsigned int* ws = (unsigned int*)d_ws;

    int npts3 = in_sizes[0];            // B*N*3
    int ntot = npts3 / 3;               // B*N
    int B = out_size / (GRID3 * FDIM);
    int N = ntot / B;
    int nbins = B * GRID3;
    int nchunks = (nbins + CHUNK - 1) / CHUNK;

    // Workspace (4B units): [0..2] minmax+nocc | [64..] bsum(1024)
    // | cursor(nbins) | idx(ntot) | occ(nbins)
    unsigned int* bsum = ws + 64;
    unsigned int* cursor = bsum + 1024;
    unsigned int* idx = cursor + nbins;
    unsigned int* occ = idx + ntot;
    size_t need_occ = (size_t)(64 + 1024 + 2 * (size_t)nbins + ntot) * 4;
    size_t need_csr = (size_t)(64 + 1024 + nbins + (size_t)ntot) * 4;

    hipLaunchKernelGGL(init_ws_kernel, dim3(1), dim3(1), 0, stream, ws);
    hipLaunchKernelGGL(minmax_kernel, dim3(512), dim3(256), 0, stream,
                       pts, npts3, ws);

    int pblocks = (ntot + 255) / 256;
    if (ws_size >= need_occ && nchunks <= 1024) {
        hipMemsetAsync(cursor, 0, (size_t)nbins * 4, stream);
        hipLaunchKernelGGL(count_kernel, dim3(pblocks), dim3(256), 0, stream,
                           pts, ws, cursor, ntot, N);
        hipLaunchKernelGGL(compact_kernel, dim3((nbins + 255) / 256), dim3(256),
                           0, stream, cursor, occ, &ws[2], nbins);
        hipLaunchKernelGGL(scanA_kernel, dim3(nchunks), dim3(256), 0, stream,
                           cursor, bsum, nbins);
        hipLaunchKernelGGL(scanB_kernel, dim3(1), dim3(1024), 0, stream,
                           bsum, nchunks);
        hipLaunchKernelGGL(scanC_kernel, dim3(nchunks), dim3(256), 0, stream,
                           cursor, bsum, nbins);
        hipLaunchKernelGGL(fill_kernel, dim3(pblocks), dim3(256), 0, stream,
                           pts, ws, cursor, idx, ntot, N);
        hipMemsetAsync(d_out, 0, (size_t)out_size * sizeof(float), stream);
        hipLaunchKernelGGL(gatherocc_kernel, dim3(GBLOCKS), dim3(256), 0,
                           stream, feat, cursor, idx, occ, &ws[2],
                           (float*)d_out);
    } else if (ws_size >= need_csr && nchunks <= 1024) {
        hipMemsetAsync(cursor, 0, (size_t)nbins * 4, stream);
        hipLaunchKernelGGL(count_kernel, dim3(pblocks), dim3(256), 0, stream,
                           pts, ws, cursor, ntot, N);
        hipLaunchKernelGGL(scanA_kernel, dim3(nchunks), dim3(256), 0, stream,
                           cursor, bsum, nbins);
        hipLaunchKernelGGL(scanB_kernel, dim3(1), dim3(1024), 0, stream,
                           bsum, nchunks);
        hipLaunchKernelGGL(scanC_kernel, dim3(nchunks), dim3(256), 0, stream,
                           cursor, bsum, nbins);
        hipLaunchKernelGGL(fill_kernel, dim3(pblocks), dim3(256), 0, stream,
                           pts, ws, cursor, idx, ntot, N);
        hipLaunchKernelGGL(gather_kernel, dim3((nbins + 3) / 4), dim3(256), 0,
                           stream, feat, cursor, idx, (float*)d_out, nbins);
    } else {
        hipMemsetAsync(d_out, 0, (size_t)out_size * sizeof(float), stream);
        hipLaunchKernelGGL(scatter_kernel, dim3((ntot + 3) / 4), dim3(256), 0,
                           stream, pts, feat, ws, (unsigned int*)d_out, ntot, N);
    }
}

// Round 8
// 279.348 us; speedup vs baseline: 1.0455x; 1.0455x over previous
//
#include <hip/hip_runtime.h>

#define GRID3 32768  // 32^3
#define FDIM 64
#define CHUNK 512    // counts per scan chunk

// Order-preserving float<->uint encoding (monotonic: enc(a)<enc(b) iff a<b)
__device__ __forceinline__ unsigned int enc_f32(float f) {
    unsigned int u = __float_as_uint(f);
    return (u & 0x80000000u) ? ~u : (u | 0x80000000u);
}
__device__ __forceinline__ float dec_f32(unsigned int u) {
    u = (u & 0x80000000u) ? (u ^ 0x80000000u) : ~u;
    return __uint_as_float(u);
}

__device__ __forceinline__ int bin_of(float x, float y, float z,
                                      float pmin, float denom) {
    // Reference op order exactly: ((v - pmin) / denom) * 32, floor.
    // Values >= 0, so int-trunc == floor.
    int vx = (int)(((x - pmin) / denom) * 32.0f);
    int vy = (int)(((y - pmin) / denom) * 32.0f);
    int vz = (int)(((z - pmin) / denom) * 32.0f);
    vx = min(max(vx, 0), 31);
    vy = min(max(vy, 0), 31);
    vz = min(max(vz, 0), 31);
    return (vx << 10) + (vy << 5) + vz;
}

__global__ void init_ws_kernel(unsigned int* ws) {
    ws[0] = 0xFFFFFFFFu;  // encoded min
    ws[1] = 0u;           // encoded max
    ws[2] = 0u;           // occupied-bin counter
}

__global__ void minmax_kernel(const float* __restrict__ pts, int n,
                              unsigned int* __restrict__ ws) {
    float lmin = INFINITY, lmax = -INFINITY;
    const float4* p4 = reinterpret_cast<const float4*>(pts);
    const int n4 = n >> 2;
    for (int i = blockIdx.x * blockDim.x + threadIdx.x; i < n4;
         i += gridDim.x * blockDim.x) {
        float4 v = p4[i];
        lmin = fminf(lmin, fminf(fminf(v.x, v.y), fminf(v.z, v.w)));
        lmax = fmaxf(lmax, fmaxf(fmaxf(v.x, v.y), fmaxf(v.z, v.w)));
    }
    for (int i = (n4 << 2) + blockIdx.x * blockDim.x + threadIdx.x; i < n;
         i += gridDim.x * blockDim.x) {
        float v = pts[i];
        lmin = fminf(lmin, v);
        lmax = fmaxf(lmax, v);
    }
    __shared__ float smin[256], smax[256];
    smin[threadIdx.x] = lmin;
    smax[threadIdx.x] = lmax;
    __syncthreads();
    for (int s = 128; s > 0; s >>= 1) {
        if (threadIdx.x < (unsigned)s) {
            smin[threadIdx.x] = fminf(smin[threadIdx.x], smin[threadIdx.x + s]);
            smax[threadIdx.x] = fmaxf(smax[threadIdx.x], smax[threadIdx.x + s]);
        }
        __syncthreads();
    }
    if (threadIdx.x == 0) {
        atomicMin(&ws[0], enc_f32(smin[0]));
        atomicMax(&ws[1], enc_f32(smax[0]));
    }
}

// Per-point histogram: 400k scattered 4B atomics over a 512KB L2-resident array.
__global__ void count_kernel(const float* __restrict__ pts,
                             const unsigned int* __restrict__ ws,
                             unsigned int* __restrict__ cnt,
                             int ntot, int N) {
    int i = blockIdx.x * blockDim.x + threadIdx.x;
    if (i >= ntot) return;
    float pmin = dec_f32(ws[0]);
    float denom = dec_f32(ws[1]) - pmin + 1e-6f;
    int bin = (i / N) * GRID3 +
              bin_of(pts[i * 3], pts[i * 3 + 1], pts[i * 3 + 2], pmin, denom);
    atomicAdd(&cnt[bin], 1u);
}

// Scan pass A: per-chunk sums.
__global__ __launch_bounds__(256)
void scanA_kernel(const unsigned int* __restrict__ cnt,
                  unsigned int* __restrict__ bsum, int nbins) {
    __shared__ unsigned int s[256];
    int base = blockIdx.x * CHUNK;
    int t = threadIdx.x;
    unsigned int a = (base + t < nbins) ? cnt[base + t] : 0u;
    unsigned int b = (base + t + 256 < nbins) ? cnt[base + t + 256] : 0u;
    s[t] = a + b;
    __syncthreads();
    for (int st = 128; st > 0; st >>= 1) {
        if (t < st) s[t] += s[t + st];
        __syncthreads();
    }
    if (t == 0) bsum[blockIdx.x] = s[0];
}

// Scan pass B: exclusive scan of chunk sums (single block, <=1024 chunks).
__global__ __launch_bounds__(1024)
void scanB_kernel(unsigned int* __restrict__ bsum, int nchunks) {
    __shared__ unsigned int s[1024];
    int t = threadIdx.x;
    unsigned int own = (t < nchunks) ? bsum[t] : 0u;
    s[t] = own;
    __syncthreads();
    for (int off = 1; off < 1024; off <<= 1) {
        unsigned int v = (t >= off) ? s[t - off] : 0u;
        __syncthreads();
        s[t] += v;
        __syncthreads();
    }
    if (t < nchunks) bsum[t] = s[t] - own;  // exclusive
}

// Scan pass C: within-chunk exclusive scan + chunk offset, in place.
__global__ __launch_bounds__(256)
void scanC_kernel(unsigned int* __restrict__ cnt,
                  const unsigned int* __restrict__ bsum, int nbins) {
    __shared__ unsigned int s[256];
    int t = threadIdx.x;
    int base = blockIdx.x * CHUNK;
    int i0 = base + 2 * t;
    unsigned int a = (i0 < nbins) ? cnt[i0] : 0u;
    unsigned int b = (i0 + 1 < nbins) ? cnt[i0 + 1] : 0u;
    unsigned int p = a + b;
    s[t] = p;
    __syncthreads();
    for (int off = 1; off < 256; off <<= 1) {
        unsigned int v = (t >= off) ? s[t - off] : 0u;
        __syncthreads();
        s[t] += v;
        __syncthreads();
    }
    unsigned int excl = s[t] - p + bsum[blockIdx.x];
    if (i0 < nbins) cnt[i0] = excl;
    if (i0 + 1 < nbins) cnt[i0 + 1] = excl + a;
}

// Fill: pos = cursor[bin]++ ; idx[pos] = point. After this pass,
// cursor[bin] == end offset of bin (== start offset of bin+1).
__global__ void fill_kernel(const float* __restrict__ pts,
                            const unsigned int* __restrict__ ws,
                            unsigned int* __restrict__ cursor,
                            unsigned int* __restrict__ idx,
                            int ntot, int N) {
    int i = blockIdx.x * blockDim.x + threadIdx.x;
    if (i >= ntot) return;
    float pmin = dec_f32(ws[0]);
    float denom = dec_f32(ws[1]) - pmin + 1e-6f;
    int bin = (i / N) * GRID3 +
              bin_of(pts[i * 3], pts[i * 3 + 1], pts[i * 3 + 2], pmin, denom);
    unsigned int pos = atomicAdd(&cursor[bin], 1u);
    idx[pos] = (unsigned int)i;
}

// Compact AFTER fill: pack {bin, start, end} of every occupied bin into one
// uint4 so the gather needs a single 16B load instead of occ->cursor hops.
__global__ void compact2_kernel(const unsigned int* __restrict__ cursor,
                                uint4* __restrict__ occ4,
                                unsigned int* __restrict__ noccp, int nbins) {
    int i = blockIdx.x * blockDim.x + threadIdx.x;
    if (i >= nbins) return;
    unsigned int s = i ? cursor[i - 1] : 0u;  // coalesced, L2-hot
    unsigned int e = cursor[i];
    if (e != s) {
        unsigned int pos = atomicAdd(noccp, 1u);
        occ4[pos] = make_uint4((unsigned int)i, s, e, 0u);
    }
}

// One wave per occupied bin; chain = occ4 -> idx batch -> feat batch (3 RTs).
// Batch-16 with index clamped to e-1: duplicate loads of the last element are
// fmax-idempotent, so even tiny bins issue 16+16 independent loads.
__global__ __launch_bounds__(256)
void gatherbin_kernel(const float* __restrict__ feat,
                      const uint4* __restrict__ occ4,
                      const unsigned int* __restrict__ noccp,
                      const unsigned int* __restrict__ idx,
                      float* __restrict__ out) {
    int wid = blockIdx.x * 4 + (threadIdx.x >> 6);
    int lane = threadIdx.x & 63;
    unsigned int nocc = *noccp;  // scalar broadcast; extra waves exit cheap
    if ((unsigned int)wid >= nocc) return;

    uint4 o = occ4[wid];         // wave-uniform 16B broadcast load
    unsigned int bin = o.x, s = o.y, e = o.z;
    const float* fl = feat + lane;

    float acc = 0.0f;  // zeros-init grid == implicit max with 0 (reference)
    for (unsigned int k = s; k < e; k += 16) {
        unsigned int p[16];
#pragma unroll
        for (int j = 0; j < 16; ++j)
            p[j] = idx[min(k + (unsigned int)j, e - 1u)];  // clamp: idempotent
        float f[16];
#pragma unroll
        for (int j = 0; j < 16; ++j)
            f[j] = fl[(size_t)p[j] * FDIM];  // 16 independent 256B loads
        float m01 = fmaxf(f[0], f[1]),  m23 = fmaxf(f[2], f[3]);
        float m45 = fmaxf(f[4], f[5]),  m67 = fmaxf(f[6], f[7]);
        float m89 = fmaxf(f[8], f[9]),  mab = fmaxf(f[10], f[11]);
        float mcd = fmaxf(f[12], f[13]), mef = fmaxf(f[14], f[15]);
        float a0 = fmaxf(fmaxf(m01, m23), fmaxf(m45, m67));
        float a1 = fmaxf(fmaxf(m89, mab), fmaxf(mcd, mef));
        acc = fmaxf(acc, fmaxf(a0, a1));
    }
    out[(size_t)bin * FDIM + lane] = acc;
}

// ---- Fallback: R4 bin-centric gather over ALL bins (proven) ----
__global__ __launch_bounds__(256)
void gather_kernel(const float* __restrict__ feat,
                   const unsigned int* __restrict__ cursor,
                   const unsigned int* __restrict__ idx,
                   float* __restrict__ out, int nbins) {
    int bin = blockIdx.x * 4 + (threadIdx.x >> 6);
    int lane = threadIdx.x & 63;
    if (bin >= nbins) return;
    unsigned int s = bin ? cursor[bin - 1] : 0u;
    unsigned int e = cursor[bin];
    const float* fl = feat + lane;
    float acc = 0.0f;
    unsigned int k = s;
    for (; k + 16 <= e; k += 16) {
        unsigned int p[16];
#pragma unroll
        for (int j = 0; j < 16; ++j) p[j] = idx[k + j];
        float f[16];
#pragma unroll
        for (int j = 0; j < 16; ++j) f[j] = fl[(size_t)p[j] * FDIM];
        float m = f[0];
#pragma unroll
        for (int j = 1; j < 16; ++j) m = fmaxf(m, f[j]);
        acc = fmaxf(acc, m);
    }
    for (; k < e; ++k)
        acc = fmaxf(acc, fl[(size_t)idx[k] * FDIM]);
    out[(size_t)bin * FDIM + lane] = acc;
}

// ---- Fallback: round-0 atomic scatter ----
__global__ void scatter_kernel(const float* __restrict__ pts,
                               const float* __restrict__ feat,
                               const unsigned int* __restrict__ ws,
                               unsigned int* __restrict__ out,
                               int ntot, int N) {
    int lane = threadIdx.x & 63;
    int p = blockIdx.x * 4 + (threadIdx.x >> 6);
    if (p >= ntot) return;
    float pmin = dec_f32(ws[0]);
    float denom = dec_f32(ws[1]) - pmin + 1e-6f;
    int gidx = bin_of(pts[p * 3], pts[p * 3 + 1], pts[p * 3 + 2], pmin, denom);
    int b = p / N;
    float f = feat[(size_t)p * FDIM + lane];
    if (f > 0.0f) {
        unsigned int* addr = out + ((size_t)b * GRID3 + gidx) * FDIM + lane;
        atomicMax(addr, __float_as_uint(f));
    }
}

extern "C" void kernel_launch(void* const* d_in, const int* in_sizes, int n_in,
                              void* d_out, int out_size, void* d_ws, size_t ws_size,
                              hipStream_t stream) {
    const float* pts = (const float*)d_in[0];
    const float* feat = (const float*)d_in[1];
    unsigned int* ws = (unsigned int*)d_ws;

    int npts3 = in_sizes[0];            // B*N*3
    int ntot = npts3 / 3;               // B*N
    int B = out_size / (GRID3 * FDIM);
    int N = ntot / B;
    int nbins = B * GRID3;
    int nchunks = (nbins + CHUNK - 1) / CHUNK;

    // Workspace (4B units): [0..2] minmax+nocc | [64..] bsum(1024)
    // | cursor(nbins) | idx(ntot) | occ4(nbins uint4, 16B-aligned)
    unsigned int* bsum = ws + 64;
    unsigned int* cursor = bsum + 1024;
    unsigned int* idx = cursor + nbins;
    size_t occ_off = ((size_t)(64 + 1024 + nbins + ntot) + 3) & ~(size_t)3;
    uint4* occ4 = (uint4*)(ws + occ_off);
    size_t need_occ = (occ_off + 4 * (size_t)nbins) * 4;
    size_t need_csr = (size_t)(64 + 1024 + nbins + (size_t)ntot) * 4;

    hipLaunchKernelGGL(init_ws_kernel, dim3(1), dim3(1), 0, stream, ws);
    hipLaunchKernelGGL(minmax_kernel, dim3(512), dim3(256), 0, stream,
                       pts, npts3, ws);

    int pblocks = (ntot + 255) / 256;
    if (ws_size >= need_occ && nchunks <= 1024) {
        hipMemsetAsync(cursor, 0, (size_t)nbins * 4, stream);
        hipLaunchKernelGGL(count_kernel, dim3(pblocks), dim3(256), 0, stream,
                           pts, ws, cursor, ntot, N);
        hipLaunchKernelGGL(scanA_kernel, dim3(nchunks), dim3(256), 0, stream,
                           cursor, bsum, nbins);
        hipLaunchKernelGGL(scanB_kernel, dim3(1), dim3(1024), 0, stream,
                           bsum, nchunks);
        hipLaunchKernelGGL(scanC_kernel, dim3(nchunks), dim3(256), 0, stream,
                           cursor, bsum, nbins);
        hipLaunchKernelGGL(fill_kernel, dim3(pblocks), dim3(256), 0, stream,
                           pts, ws, cursor, idx, ntot, N);
        hipLaunchKernelGGL(compact2_kernel, dim3((nbins + 255) / 256),
                           dim3(256), 0, stream, cursor, occ4, &ws[2], nbins);
        hipMemsetAsync(d_out, 0, (size_t)out_size * sizeof(float), stream);
        hipLaunchKernelGGL(gatherbin_kernel, dim3((nbins + 3) / 4), dim3(256),
                           0, stream, feat, occ4, &ws[2], idx, (float*)d_out);
    } else if (ws_size >= need_csr && nchunks <= 1024) {
        hipMemsetAsync(cursor, 0, (size_t)nbins * 4, stream);
        hipLaunchKernelGGL(count_kernel, dim3(pblocks), dim3(256), 0, stream,
                           pts, ws, cursor, ntot, N);
        hipLaunchKernelGGL(scanA_kernel, dim3(nchunks), dim3(256), 0, stream,
                           cursor, bsum, nbins);
        hipLaunchKernelGGL(scanB_kernel, dim3(1), dim3(1024), 0, stream,
                           bsum, nchunks);
        hipLaunchKernelGGL(scanC_kernel, dim3(nchunks), dim3(256), 0, stream,
                           cursor, bsum, nbins);
        hipLaunchKernelGGL(fill_kernel, dim3(pblocks), dim3(256), 0, stream,
                           pts, ws, cursor, idx, ntot, N);
        hipLaunchKernelGGL(gather_kernel, dim3((nbins + 3) / 4), dim3(256), 0,
                           stream, feat, cursor, idx, (float*)d_out, nbins);
    } else {
        hipMemsetAsync(d_out, 0, (size_t)out_size * sizeof(float), stream);
        hipLaunchKernelGGL(scatter_kernel, dim3((ntot + 3) / 4), dim3(256), 0,
                           stream, pts, feat, ws, (unsigned int*)d_out, ntot, N);
    }
}

// Round 9
// 275.391 us; speedup vs baseline: 1.0605x; 1.0144x over previous
//
#include <hip/hip_runtime.h>

#define GRID3 32768  // 32^3
#define FDIM 64
#define CHUNK 512    // counts per scan chunk
#define SPLIT 128u   // max points per gather work-item (hot-bin splitting)

// Order-preserving float<->uint encoding (monotonic: enc(a)<enc(b) iff a<b)
__device__ __forceinline__ unsigned int enc_f32(float f) {
    unsigned int u = __float_as_uint(f);
    return (u & 0x80000000u) ? ~u : (u | 0x80000000u);
}
__device__ __forceinline__ float dec_f32(unsigned int u) {
    u = (u & 0x80000000u) ? (u ^ 0x80000000u) : ~u;
    return __uint_as_float(u);
}

__device__ __forceinline__ int bin_of(float x, float y, float z,
                                      float pmin, float denom) {
    // Reference op order exactly: ((v - pmin) / denom) * 32, floor.
    // Values >= 0, so int-trunc == floor.
    int vx = (int)(((x - pmin) / denom) * 32.0f);
    int vy = (int)(((y - pmin) / denom) * 32.0f);
    int vz = (int)(((z - pmin) / denom) * 32.0f);
    vx = min(max(vx, 0), 31);
    vy = min(max(vy, 0), 31);
    vz = min(max(vz, 0), 31);
    return (vx << 10) + (vy << 5) + vz;
}

__global__ void init_ws_kernel(unsigned int* ws) {
    ws[0] = 0xFFFFFFFFu;  // encoded min
    ws[1] = 0u;           // encoded max
    ws[2] = 0u;           // gather work-item counter
}

__global__ void minmax_kernel(const float* __restrict__ pts, int n,
                              unsigned int* __restrict__ ws) {
    float lmin = INFINITY, lmax = -INFINITY;
    const float4* p4 = reinterpret_cast<const float4*>(pts);
    const int n4 = n >> 2;
    for (int i = blockIdx.x * blockDim.x + threadIdx.x; i < n4;
         i += gridDim.x * blockDim.x) {
        float4 v = p4[i];
        lmin = fminf(lmin, fminf(fminf(v.x, v.y), fminf(v.z, v.w)));
        lmax = fmaxf(lmax, fmaxf(fmaxf(v.x, v.y), fmaxf(v.z, v.w)));
    }
    for (int i = (n4 << 2) + blockIdx.x * blockDim.x + threadIdx.x; i < n;
         i += gridDim.x * blockDim.x) {
        float v = pts[i];
        lmin = fminf(lmin, v);
        lmax = fmaxf(lmax, v);
    }
    __shared__ float smin[256], smax[256];
    smin[threadIdx.x] = lmin;
    smax[threadIdx.x] = lmax;
    __syncthreads();
    for (int s = 128; s > 0; s >>= 1) {
        if (threadIdx.x < (unsigned)s) {
            smin[threadIdx.x] = fminf(smin[threadIdx.x], smin[threadIdx.x + s]);
            smax[threadIdx.x] = fmaxf(smax[threadIdx.x], smax[threadIdx.x + s]);
        }
        __syncthreads();
    }
    if (threadIdx.x == 0) {
        atomicMin(&ws[0], enc_f32(smin[0]));
        atomicMax(&ws[1], enc_f32(smax[0]));
    }
}

// Histogram + per-point bin cache: fill no longer re-reads pts or divides.
__global__ void count_kernel(const float* __restrict__ pts,
                             const unsigned int* __restrict__ ws,
                             unsigned int* __restrict__ cnt,
                             unsigned int* __restrict__ pbin,
                             int ntot, int N) {
    int i = blockIdx.x * blockDim.x + threadIdx.x;
    if (i >= ntot) return;
    float pmin = dec_f32(ws[0]);
    float denom = dec_f32(ws[1]) - pmin + 1e-6f;
    unsigned int bin = (unsigned int)((i / N) * GRID3 +
        bin_of(pts[i * 3], pts[i * 3 + 1], pts[i * 3 + 2], pmin, denom));
    pbin[i] = bin;
    atomicAdd(&cnt[bin], 1u);
}

// Scan pass A: per-chunk sums.
__global__ __launch_bounds__(256)
void scanA_kernel(const unsigned int* __restrict__ cnt,
                  unsigned int* __restrict__ bsum, int nbins) {
    __shared__ unsigned int s[256];
    int base = blockIdx.x * CHUNK;
    int t = threadIdx.x;
    unsigned int a = (base + t < nbins) ? cnt[base + t] : 0u;
    unsigned int b = (base + t + 256 < nbins) ? cnt[base + t + 256] : 0u;
    s[t] = a + b;
    __syncthreads();
    for (int st = 128; st > 0; st >>= 1) {
        if (t < st) s[t] += s[t + st];
        __syncthreads();
    }
    if (t == 0) bsum[blockIdx.x] = s[0];
}

// Scan pass B: exclusive scan of chunk sums (single block, <=1024 chunks).
__global__ __launch_bounds__(1024)
void scanB_kernel(unsigned int* __restrict__ bsum, int nchunks) {
    __shared__ unsigned int s[1024];
    int t = threadIdx.x;
    unsigned int own = (t < nchunks) ? bsum[t] : 0u;
    s[t] = own;
    __syncthreads();
    for (int off = 1; off < 1024; off <<= 1) {
        unsigned int v = (t >= off) ? s[t - off] : 0u;
        __syncthreads();
        s[t] += v;
        __syncthreads();
    }
    if (t < nchunks) bsum[t] = s[t] - own;  // exclusive
}

// Scan pass C + fused compaction: writes start offsets in place AND emits
// gather work-items {bin, start, end, shared_flag}. Bins > SPLIT points are
// split into multiple items (shared_flag=1 -> atomicMax merge in gather).
__global__ __launch_bounds__(256)
void scanC_kernel(unsigned int* __restrict__ cnt,
                  const unsigned int* __restrict__ bsum,
                  uint4* __restrict__ occ4,
                  unsigned int* __restrict__ noccp, int nbins) {
    __shared__ unsigned int s[256];
    int t = threadIdx.x;
    int base = blockIdx.x * CHUNK;
    int i0 = base + 2 * t;
    unsigned int a = (i0 < nbins) ? cnt[i0] : 0u;
    unsigned int b = (i0 + 1 < nbins) ? cnt[i0 + 1] : 0u;
    unsigned int p = a + b;
    s[t] = p;
    __syncthreads();
    for (int off = 1; off < 256; off <<= 1) {
        unsigned int v = (t >= off) ? s[t - off] : 0u;
        __syncthreads();
        s[t] += v;
        __syncthreads();
    }
    unsigned int excl = s[t] - p + bsum[blockIdx.x];
    if (i0 < nbins) cnt[i0] = excl;
    if (i0 + 1 < nbins) cnt[i0 + 1] = excl + a;

    // Emit work-items (rare multi-emit for hot bins).
    if (i0 < nbins && a) {
        if (a <= SPLIT) {
            unsigned int pos = atomicAdd(noccp, 1u);
            occ4[pos] = make_uint4((unsigned int)i0, excl, excl + a, 0u);
        } else {
            for (unsigned int off = 0; off < a; off += SPLIT) {
                unsigned int pos = atomicAdd(noccp, 1u);
                occ4[pos] = make_uint4((unsigned int)i0, excl + off,
                                       excl + min(off + SPLIT, a), 1u);
            }
        }
    }
    if (i0 + 1 < nbins && b) {
        unsigned int st = excl + a;
        if (b <= SPLIT) {
            unsigned int pos = atomicAdd(noccp, 1u);
            occ4[pos] = make_uint4((unsigned int)(i0 + 1), st, st + b, 0u);
        } else {
            for (unsigned int off = 0; off < b; off += SPLIT) {
                unsigned int pos = atomicAdd(noccp, 1u);
                occ4[pos] = make_uint4((unsigned int)(i0 + 1), st + off,
                                       st + min(off + SPLIT, b), 1u);
            }
        }
    }
}

// Fill from cached bins: sequential pbin read, no pts re-read, no division.
__global__ void fill_kernel(const unsigned int* __restrict__ pbin,
                            unsigned int* __restrict__ cursor,
                            unsigned int* __restrict__ idx, int ntot) {
    int i = blockIdx.x * blockDim.x + threadIdx.x;
    if (i >= ntot) return;
    unsigned int bin = pbin[i];
    unsigned int pos = atomicAdd(&cursor[bin], 1u);
    idx[pos] = (unsigned int)i;
}

// Gather: 16-lane group per work-item; feat row = 16 lanes x float4 so the
// channel max is lane-local (no cross-lane reduction). 4 independent bin
// chains per wave, 16 KB in flight per wave. Clamp-16 batches make tiny bins
// issue full-width load batches (duplicates are fmax-idempotent).
__global__ __launch_bounds__(256)
void gatherg16_kernel(const float4* __restrict__ feat4,
                      const uint4* __restrict__ occ4,
                      const unsigned int* __restrict__ noccp,
                      const unsigned int* __restrict__ idx,
                      float4* __restrict__ out4) {
    unsigned int gslot = blockIdx.x * 16u + (threadIdx.x >> 4);
    int l16 = threadIdx.x & 15;
    int gbase = threadIdx.x & 48;  // group's first lane within the wave's 64
    unsigned int nocc = *noccp;
    if (gslot >= nocc) return;

    uint4 o = occ4[gslot];  // 16B broadcast within the group
    unsigned int bin = o.x, s = o.y, e = o.z;

    float4 acc = make_float4(0.f, 0.f, 0.f, 0.f);  // zeros-init == ref max w/ 0
    for (unsigned int k = s; k < e; k += 16u) {
        unsigned int pj = idx[min(k + (unsigned int)l16, e - 1u)];
#pragma unroll
        for (int j = 0; j < 16; ++j) {
            unsigned int pt = __shfl(pj, gbase + j);        // group-local src
            float4 f = feat4[(size_t)pt * 16 + l16];        // 16B per lane
            acc.x = fmaxf(acc.x, f.x);
            acc.y = fmaxf(acc.y, f.y);
            acc.z = fmaxf(acc.z, f.z);
            acc.w = fmaxf(acc.w, f.w);
        }
    }
    if (o.w == 0u) {
        out4[(size_t)bin * 16 + l16] = acc;  // exclusive owner: plain store
    } else {
        // Split bin: merge via per-component atomicMax (positive-float trick).
        unsigned int* ob =
            (unsigned int*)(out4 + (size_t)bin * 16 + l16);
        if (acc.x > 0.f) atomicMax(ob + 0, __float_as_uint(acc.x));
        if (acc.y > 0.f) atomicMax(ob + 1, __float_as_uint(acc.y));
        if (acc.z > 0.f) atomicMax(ob + 2, __float_as_uint(acc.z));
        if (acc.w > 0.f) atomicMax(ob + 3, __float_as_uint(acc.w));
    }
}

// ---- Fallback: R4 proven CSR path (pts-based fill + wave-per-bin gather) ----
__global__ void fillpts_kernel(const float* __restrict__ pts,
                               const unsigned int* __restrict__ ws,
                               unsigned int* __restrict__ cursor,
                               unsigned int* __restrict__ idx,
                               int ntot, int N) {
    int i = blockIdx.x * blockDim.x + threadIdx.x;
    if (i >= ntot) return;
    float pmin = dec_f32(ws[0]);
    float denom = dec_f32(ws[1]) - pmin + 1e-6f;
    int bin = (i / N) * GRID3 +
              bin_of(pts[i * 3], pts[i * 3 + 1], pts[i * 3 + 2], pmin, denom);
    unsigned int pos = atomicAdd(&cursor[bin], 1u);
    idx[pos] = (unsigned int)i;
}

__global__ __launch_bounds__(256)
void gather_kernel(const float* __restrict__ feat,
                   const unsigned int* __restrict__ cursor,
                   const unsigned int* __restrict__ idx,
                   float* __restrict__ out, int nbins) {
    int bin = blockIdx.x * 4 + (threadIdx.x >> 6);
    int lane = threadIdx.x & 63;
    if (bin >= nbins) return;
    unsigned int s = bin ? cursor[bin - 1] : 0u;
    unsigned int e = cursor[bin];
    const float* fl = feat + lane;
    float acc = 0.0f;
    unsigned int k = s;
    for (; k + 16 <= e; k += 16) {
        unsigned int p[16];
#pragma unroll
        for (int j = 0; j < 16; ++j) p[j] = idx[k + j];
        float f[16];
#pragma unroll
        for (int j = 0; j < 16; ++j) f[j] = fl[(size_t)p[j] * FDIM];
        float m = f[0];
#pragma unroll
        for (int j = 1; j < 16; ++j) m = fmaxf(m, f[j]);
        acc = fmaxf(acc, m);
    }
    for (; k < e; ++k)
        acc = fmaxf(acc, fl[(size_t)idx[k] * FDIM]);
    out[(size_t)bin * FDIM + lane] = acc;
}

// Plain scanC (no compaction) for the fallback path.
__global__ __launch_bounds__(256)
void scanCp_kernel(unsigned int* __restrict__ cnt,
                   const unsigned int* __restrict__ bsum, int nbins) {
    __shared__ unsigned int s[256];
    int t = threadIdx.x;
    int base = blockIdx.x * CHUNK;
    int i0 = base + 2 * t;
    unsigned int a = (i0 < nbins) ? cnt[i0] : 0u;
    unsigned int b = (i0 + 1 < nbins) ? cnt[i0 + 1] : 0u;
    unsigned int p = a + b;
    s[t] = p;
    __syncthreads();
    for (int off = 1; off < 256; off <<= 1) {
        unsigned int v = (t >= off) ? s[t - off] : 0u;
        __syncthreads();
        s[t] += v;
        __syncthreads();
    }
    unsigned int excl = s[t] - p + bsum[blockIdx.x];
    if (i0 < nbins) cnt[i0] = excl;
    if (i0 + 1 < nbins) cnt[i0 + 1] = excl + a;
}

// ---- Fallback: round-0 atomic scatter ----
__global__ void scatter_kernel(const float* __restrict__ pts,
                               const float* __restrict__ feat,
                               const unsigned int* __restrict__ ws,
                               unsigned int* __restrict__ out,
                               int ntot, int N) {
    int lane = threadIdx.x & 63;
    int p = blockIdx.x * 4 + (threadIdx.x >> 6);
    if (p >= ntot) return;
    float pmin = dec_f32(ws[0]);
    float denom = dec_f32(ws[1]) - pmin + 1e-6f;
    int gidx = bin_of(pts[p * 3], pts[p * 3 + 1], pts[p * 3 + 2], pmin, denom);
    int b = p / N;
    float f = feat[(size_t)p * FDIM + lane];
    if (f > 0.0f) {
        unsigned int* addr = out + ((size_t)b * GRID3 + gidx) * FDIM + lane;
        atomicMax(addr, __float_as_uint(f));
    }
}

extern "C" void kernel_launch(void* const* d_in, const int* in_sizes, int n_in,
                              void* d_out, int out_size, void* d_ws, size_t ws_size,
                              hipStream_t stream) {
    const float* pts = (const float*)d_in[0];
    const float* feat = (const float*)d_in[1];
    unsigned int* ws = (unsigned int*)d_ws;

    int npts3 = in_sizes[0];            // B*N*3
    int ntot = npts3 / 3;               // B*N
    int B = out_size / (GRID3 * FDIM);
    int N = ntot / B;
    int nbins = B * GRID3;
    int nchunks = (nbins + CHUNK - 1) / CHUNK;

    // Work-item capacity: every occupied bin + split-overflow.
    int wi_cap = nbins + ntot / (int)SPLIT + 16;

    // Workspace (4B units): [0..2] | bsum(1024) | cursor(nbins) | idx(ntot)
    // | pbin(ntot) | occ4(wi_cap uint4, 16B-aligned)
    unsigned int* bsum = ws + 64;
    unsigned int* cursor = bsum + 1024;
    unsigned int* idx = cursor + nbins;
    unsigned int* pbin = idx + ntot;
    size_t occ_off = ((size_t)(64 + 1024 + nbins + 2 * (size_t)ntot) + 3) &
                     ~(size_t)3;
    uint4* occ4 = (uint4*)(ws + occ_off);
    size_t need_g16 = (occ_off + 4 * (size_t)wi_cap) * 4;
    size_t need_csr = (size_t)(64 + 1024 + nbins + (size_t)ntot) * 4;

    hipLaunchKernelGGL(init_ws_kernel, dim3(1), dim3(1), 0, stream, ws);
    hipLaunchKernelGGL(minmax_kernel, dim3(512), dim3(256), 0, stream,
                       pts, npts3, ws);

    int pblocks = (ntot + 255) / 256;
    if (ws_size >= need_g16 && nchunks <= 1024) {
        hipMemsetAsync(cursor, 0, (size_t)nbins * 4, stream);
        hipLaunchKernelGGL(count_kernel, dim3(pblocks), dim3(256), 0, stream,
                           pts, ws, cursor, pbin, ntot, N);
        hipLaunchKernelGGL(scanA_kernel, dim3(nchunks), dim3(256), 0, stream,
                           cursor, bsum, nbins);
        hipLaunchKernelGGL(scanB_kernel, dim3(1), dim3(1024), 0, stream,
                           bsum, nchunks);
        hipLaunchKernelGGL(scanC_kernel, dim3(nchunks), dim3(256), 0, stream,
                           cursor, bsum, occ4, &ws[2], nbins);
        hipLaunchKernelGGL(fill_kernel, dim3(pblocks), dim3(256), 0, stream,
                           pbin, cursor, idx, ntot);
        hipMemsetAsync(d_out, 0, (size_t)out_size * sizeof(float), stream);
        int gblocks = (wi_cap + 15) / 16;
        hipLaunchKernelGGL(gatherg16_kernel, dim3(gblocks), dim3(256), 0,
                           stream, (const float4*)feat, occ4, &ws[2], idx,
                           (float4*)d_out);
    } else if (ws_size >= need_csr && nchunks <= 1024) {
        hipMemsetAsync(cursor, 0, (size_t)nbins * 4, stream);
        hipLaunchKernelGGL(count_kernel, dim3(pblocks), dim3(256), 0, stream,
                           pts, ws, cursor, cursor /*pbin unused overlap-safe:
                           writes then atomics to same array would corrupt; use
                           pts-based fallback fill instead*/, ntot, N);
        // NOTE: fallback path ignores pbin; count only needs cnt. Recompute
        // cleanly: cnt was corrupted by the aliased pbin write above is NOT
        // acceptable -> zero and recount without pbin aliasing.
        hipMemsetAsync(cursor, 0, (size_t)nbins * 4, stream);
        hipLaunchKernelGGL(scatter_kernel, dim3(1), dim3(64), 0, stream,
                           pts, feat, ws, (unsigned int*)d_out, 0, N);  // no-op
        hipMemsetAsync(cursor, 0, (size_t)nbins * 4, stream);
        hipLaunchKernelGGL(count_kernel, dim3(pblocks), dim3(256), 0, stream,
                           pts, ws, cursor, idx /*scratch, overwritten later*/,
                           ntot, N);
        hipLaunchKernelGGL(scanA_kernel, dim3(nchunks), dim3(256), 0, stream,
                           cursor, bsum, nbins);
        hipLaunchKernelGGL(scanB_kernel, dim3(1), dim3(1024), 0, stream,
                           bsum, nchunks);
        hipLaunchKernelGGL(scanCp_kernel, dim3(nchunks), dim3(256), 0, stream,
                           cursor, bsum, nbins);
        hipLaunchKernelGGL(fillpts_kernel, dim3(pblocks), dim3(256), 0, stream,
                           pts, ws, cursor, idx, ntot, N);
        hipLaunchKernelGGL(gather_kernel, dim3((nbins + 3) / 4), dim3(256), 0,
                           stream, feat, cursor, idx, (float*)d_out, nbins);
    } else {
        hipMemsetAsync(d_out, 0, (size_t)out_size * sizeof(float), stream);
        hipLaunchKernelGGL(scatter_kernel, dim3((ntot + 3) / 4), dim3(256), 0,
                           stream, pts, feat, ws, (unsigned int*)d_out, ntot, N);
    }
}